// Round 9
// baseline (221.413 us; speedup 1.0000x reference)
//
#include <hip/hip_runtime.h>
#include <hip/hip_bf16.h>
#include <math.h>

#define NQ     16384
#define CDIM   256
#define NHEADS 8
#define NPTS   8
#define NLVL   2
#define HH     128
#define WWID   128
#define DHEAD  32
#define NCAT   384   // fused off(256) + attn(128) projection width

// padded fp8 value-map geometry: (l, h, 130, 130, 32) fp8, zero border
#define PW        130
#define CELLB     32                    // bytes per cell (32 dims x fp8)
#define ROWB      (PW * CELLB)          // 4160 B per padded row
#define MAPB      (PW * PW * CELLB)     // 540800 B per (l,h) map
#define V2BYTES   (NLVL * NHEADS * MAPB)        // 8,652,800
#define MEMSET_BLKS 2113                // ceil(V2BYTES / (256*16))

typedef __bf16 bf16_t;
typedef __bf16 bf16x8 __attribute__((ext_vector_type(8)));
typedef __bf16 bf16x4 __attribute__((ext_vector_type(4)));
typedef float  f32x4  __attribute__((ext_vector_type(4)));
typedef float  f32x2  __attribute__((ext_vector_type(2)));

typedef __attribute__((address_space(1))) const uint32_t gau32;
typedef __attribute__((address_space(3))) uint32_t lau32;

__device__ __forceinline__ bf16_t f2b(float f) { return (bf16_t)f; }

// ---------------------------------------------------------------------------
// One dispatch: zero v2 (incl. border) + LDS-transpose all weights to bf16.
// For W_val, rows of Wt_val are PERMUTED so that the v-proj epilogue's four
// j-accumulators map to 4 consecutive d within one head:
//   n -> p(n) = (n&~63) | ((n&3)<<4) | ((n&63)>>2)
// ---------------------------------------------------------------------------
__global__ __launch_bounds__(256) void prep_k(const float* __restrict__ W_val,
                                              const float* __restrict__ W_off,
                                              const float* __restrict__ W_attn,
                                              const float* __restrict__ W_out,
                                              unsigned char* __restrict__ v2,
                                              bf16_t* __restrict__ Wt_val,
                                              bf16_t* __restrict__ Wt_qa,
                                              bf16_t* __restrict__ Wt_out) {
    const int b = blockIdx.x;
    if (b < MEMSET_BLKS) {
        size_t off = ((size_t)b * 256 + threadIdx.x) * 16;
        if (off < V2BYTES)
            *reinterpret_cast<uint4*>(v2 + off) = make_uint4(0, 0, 0, 0);
        return;
    }
    const int tb = b - MEMSET_BLKS;
    const float* W; bf16_t* Wt; int N, t; bool permute = false;
    if (tb < 64)       { W = W_val;  Wt = Wt_val;            N = 256; t = tb;       permute = true; }
    else if (tb < 128) { W = W_off;  Wt = Wt_qa;             N = 256; t = tb - 64;  }
    else if (tb < 160) { W = W_attn; Wt = Wt_qa + 256 * 256; N = 128; t = tb - 128; }
    else               { W = W_out;  Wt = Wt_out;            N = 256; t = tb - 160; }
    const int ntn = N >> 5;
    const int k0 = (t / ntn) * 32, n0 = (t % ntn) * 32;
    const int tx = threadIdx.x & 31, ty = threadIdx.x >> 5;   // 32 x 8
    __shared__ float s[32][33];
#pragma unroll
    for (int i = 0; i < 4; ++i)
        s[ty + 8 * i][tx] = W[(size_t)(k0 + ty + 8 * i) * N + n0 + tx];
    __syncthreads();
#pragma unroll
    for (int i = 0; i < 4; ++i) {
        const int n = n0 + ty + 8 * i;                 // logical col
        const int p = permute ? ((n & ~63) | ((n & 3) << 4) | ((n & 63) >> 2)) : n;
        Wt[(size_t)p * 256 + k0 + tx] = f2b(s[tx][ty + 8 * i]);
    }
}

// ---------------------------------------------------------------------------
// GEMM body with XOR-swizzled LDS tiles (conflict-free staging + frag reads).
// A_MODE: 0 = bf16 A (global_load_lds), 1 = fp32 A, 2 = fp32 A + A2 summed.
// fp32 A staging is COALESCED: 16 consecutive lanes cover one row's 256 B
// k-segment (lane -> row=tid>>4, colf=(tid&15)*4; 8 row-batches of 16).
// PERM_V: epilogue packs 4 fp8 bytes -> 1 dword into the padded v2 map.
// ---------------------------------------------------------------------------
template <int A_MODE, bool OUT_BF16, bool ADD_SRC, bool PERM_V>
__device__ __forceinline__ void gemm_body(bf16_t (&As)[128][64], bf16_t (&Bs)[128][64],
                                          int bidx, int bidy,
                                          const void* __restrict__ Aptr,
                                          const void* __restrict__ Aptr2,
                                          const bf16_t* __restrict__ Bt,
                                          const float* __restrict__ bias,
                                          const float* __restrict__ bias2,
                                          int Nsplit,
                                          const float* __restrict__ addsrc,
                                          void* __restrict__ Cout,
                                          int N, int K) {
    const int tid  = threadIdx.x;
    const int wave = tid >> 6;
    const int lane = tid & 63;
    const int rowBase = bidy * 128;
    const int colBase = bidx * 128;
    const int wm = (wave & 1) * 64;
    const int wn = (wave >> 1) * 64;
    const int fr = lane & 15;
    const int fq = lane >> 4;

    f32x4 acc[4][4] = {};

    const int lrow = lane >> 3;                       // 0..7
    const int scol = ((lane & 7) ^ lrow) * 8;         // swizzled k-offset (elems)

    // coalesced fp32-staging lane map
    const int sr = tid >> 4;                          // row within 16-row batch
    const int sc = (tid & 15) * 4;                    // float col 0..60
    const int spg = ((tid & 15) >> 1);                // 16B granule 0..7
    const int shalf = (tid & 15) & 1;                 // 8B half

    for (int k0 = 0; k0 < K; k0 += 64) {
        __syncthreads();
        if (A_MODE != 0) {
#pragma unroll
            for (int u = 0; u < 8; ++u) {
                const int r = sr + u * 16;
                const float* ap = (const float*)Aptr + (size_t)(rowBase + r) * K + k0 + sc;
                float4 f = *reinterpret_cast<const float4*>(ap);
                if (A_MODE == 2) {
                    const float* ap2 = (const float*)Aptr2 + (size_t)(rowBase + r) * K + k0 + sc;
                    float4 g = *reinterpret_cast<const float4*>(ap2);
                    f.x += g.x; f.y += g.y; f.z += g.z; f.w += g.w;
                }
                bf16x4 bv;
                bv[0] = f2b(f.x); bv[1] = f2b(f.y); bv[2] = f2b(f.z); bv[3] = f2b(f.w);
                const int pg = spg ^ (r & 7);
                *reinterpret_cast<bf16x4*>(&As[r][pg * 8 + shalf * 4]) = bv;
            }
        } else {
            const bf16_t* Abf = (const bf16_t*)Aptr;
#pragma unroll
            for (int t = 0; t < 4; ++t) {
                const bf16_t* src =
                    Abf + (size_t)(rowBase + wave * 32 + t * 8 + lrow) * K + k0 + scol;
                __builtin_amdgcn_global_load_lds((gau32*)src,
                                                 (lau32*)&As[wave * 32 + t * 8][0],
                                                 16, 0, 0);
            }
        }
#pragma unroll
        for (int t = 0; t < 4; ++t) {
            const bf16_t* src =
                Bt + (size_t)(colBase + wave * 32 + t * 8 + lrow) * K + k0 + scol;
            __builtin_amdgcn_global_load_lds((gau32*)src,
                                             (lau32*)&Bs[wave * 32 + t * 8][0],
                                             16, 0, 0);
        }
        __syncthreads();
#pragma unroll
        for (int ks = 0; ks < 2; ++ks) {
            const int gk = ((ks * 4 + fq) ^ (fr & 7)) * 8;  // swizzled read granule
            bf16x8 af[4], bfr[4];
#pragma unroll
            for (int i = 0; i < 4; ++i)
                af[i] = *reinterpret_cast<const bf16x8*>(&As[wm + i * 16 + fr][gk]);
#pragma unroll
            for (int j = 0; j < 4; ++j)
                bfr[j] = *reinterpret_cast<const bf16x8*>(&Bs[wn + j * 16 + fr][gk]);
#pragma unroll
            for (int i = 0; i < 4; ++i)
#pragma unroll
                for (int j = 0; j < 4; ++j)
                    acc[i][j] = __builtin_amdgcn_mfma_f32_16x16x32_bf16(af[i], bfr[j],
                                                                        acc[i][j], 0, 0, 0);
        }
    }

    if (PERM_V) {
        // logical cols for j=0..3 are lbase..lbase+3 (4 consecutive d, 1 head)
        const int lbase = colBase + wn + fr * 4;
        const float bv0 = bias[lbase], bv1 = bias[lbase + 1];
        const float bv2 = bias[lbase + 2], bv3 = bias[lbase + 3];
        const int hh = (lbase >> 5) & 7;
        const int dbase = lbase & 31;
        unsigned char* outp = (unsigned char*)Cout;
#pragma unroll
        for (int i = 0; i < 4; ++i) {
#pragma unroll
            for (int r = 0; r < 4; ++r) {
                const int row = rowBase + wm + i * 16 + fq * 4 + r;
                const int lv = row >> 14, cell = row & 16383;
                const int y = cell >> 7, x = cell & 127;
                uint32_t pk = __builtin_amdgcn_cvt_pk_fp8_f32(
                    acc[i][0][r] + bv0, acc[i][1][r] + bv1, 0, false);
                pk = (uint32_t)__builtin_amdgcn_cvt_pk_fp8_f32(
                    acc[i][2][r] + bv2, acc[i][3][r] + bv3, pk, true);
                *reinterpret_cast<uint32_t*>(
                    outp + (size_t)(lv * NHEADS + hh) * MAPB
                         + (size_t)(y + 1) * ROWB + (x + 1) * CELLB + dbase) = pk;
            }
        }
        return;
    }

    // epilogue: D[row = fq*4 + r][col = fr] per 16x16 tile
#pragma unroll
    for (int j = 0; j < 4; ++j) {
        const int col = colBase + wn + j * 16 + fr;
        const float bv = (col < Nsplit) ? bias[col] : bias2[col - Nsplit];
#pragma unroll
        for (int i = 0; i < 4; ++i) {
#pragma unroll
            for (int r = 0; r < 4; ++r) {
                const int row = rowBase + wm + i * 16 + fq * 4 + r;
                float vv = acc[i][j][r] + bv;
                if (ADD_SRC) vv += addsrc[(size_t)row * N + col];
                if (OUT_BF16)
                    ((bf16_t*)Cout)[(size_t)row * N + col] = f2b(vv);
                else
                    ((float*)Cout)[(size_t)row * N + col] = vv;
            }
        }
    }
}

// ---------------------------------------------------------------------------
// Fused projections. blocks 0..511: v-proj (fp32 -> padded fp8 v2, permuted
// Wt_val) | 512..895: (q+qpos) @ [W_off|W_attn] -> cbuf f32.
// ---------------------------------------------------------------------------
__global__ __launch_bounds__(256, 4) void fused_proj_k(const float* __restrict__ value,
                                                       const float* __restrict__ query,
                                                       const float* __restrict__ query_pos,
                                                       const bf16_t* __restrict__ Wt_val,
                                                       const bf16_t* __restrict__ Wt_qa,
                                                       const float* __restrict__ b_val,
                                                       const float* __restrict__ b_off,
                                                       const float* __restrict__ b_attn,
                                                       unsigned char* __restrict__ v2,
                                                       float* __restrict__ cbuf) {
    __shared__ __align__(16) bf16_t As[128][64];
    __shared__ __align__(16) bf16_t Bs[128][64];
    const int b = blockIdx.x;
    if (b < 512) {
        const int bidy = (b >> 4) * 8 + (b & 7);
        const int bidx = (b >> 3) & 1;
        gemm_body<1, true, false, true>(As, Bs, bidx, bidy, value, nullptr,
                                        Wt_val, b_val, b_val, 256, nullptr, v2,
                                        CDIM, CDIM);
    } else {
        const int b2 = b - 512;
        const int bidy = (b2 / 24) * 8 + (b2 & 7);
        const int bidx = (b2 >> 3) % 3;
        gemm_body<2, false, false, false>(As, Bs, bidx, bidy, query, query_pos,
                                          Wt_qa, b_off, b_attn, 256, nullptr, cbuf,
                                          NCAT, CDIM);
    }
}

// ---------------------------------------------------------------------------
// Output projection: out = tmp @ W_out + b_out + query
// ---------------------------------------------------------------------------
__global__ __launch_bounds__(256, 3) void outproj_k(const bf16_t* __restrict__ tmp,
                                                    const bf16_t* __restrict__ Wt_out,
                                                    const float* __restrict__ b_out,
                                                    const float* __restrict__ query,
                                                    float* __restrict__ out) {
    __shared__ __align__(16) bf16_t As[128][64];
    __shared__ __align__(16) bf16_t Bs[128][64];
    const int b = blockIdx.x;
    const int bidy = (b >> 4) * 8 + (b & 7);
    const int bidx = (b >> 3) & 1;
    gemm_body<0, false, true, false>(As, Bs, bidx, bidy, tmp, nullptr,
                                     Wt_out, b_out, b_out, 256, query, out,
                                     CDIM, CDIM);
}

// ---------------------------------------------------------------------------
// Bilinear sampling on the zero-padded fp8 map. head = blockIdx % 8 -> XCD.
// Clamped taps land on zero cells => unconditional corner weights.
// fp8 -> f32 via v_cvt_pk_f32_fp8 (2 elems/inst), float2 accumulate.
// ---------------------------------------------------------------------------
__device__ __forceinline__ void acc_tap(uint2 u, float w, f32x2* acc2) {
    acc2[0] += __builtin_amdgcn_cvt_pk_f32_fp8((int)u.x, false) * w;
    acc2[1] += __builtin_amdgcn_cvt_pk_f32_fp8((int)u.x, true)  * w;
    acc2[2] += __builtin_amdgcn_cvt_pk_f32_fp8((int)u.y, false) * w;
    acc2[3] += __builtin_amdgcn_cvt_pk_f32_fp8((int)u.y, true)  * w;
}

__global__ __launch_bounds__(256) void sample_k(const unsigned char* __restrict__ v2,
                                                const float* __restrict__ cbuf,
                                                const float* __restrict__ refp,
                                                bf16_t* __restrict__ tmp) {
    const int b    = blockIdx.x;
    const int h    = b & 7;          // head -> XCD (round-robin dispatch)
    const int qblk = b >> 3;
    const int tid  = threadIdx.x;
    const int qloc = tid >> 2;
    const int ck   = tid & 3;
    const int q    = qblk * 64 + qloc;

    const float* qrow = cbuf + (size_t)q * NCAT;
    const float4 rp = *reinterpret_cast<const float4*>(refp + (size_t)q * 4);

    // ---- softmax over the 16 logits of (q,h), in-register ----
    const float* attp = qrow + 256 + h * 16;
    float4 A0 = *reinterpret_cast<const float4*>(attp);
    float4 A1 = *reinterpret_cast<const float4*>(attp + 4);
    float4 A2 = *reinterpret_cast<const float4*>(attp + 8);
    float4 A3 = *reinterpret_cast<const float4*>(attp + 12);
    float e[16] = {A0.x, A0.y, A0.z, A0.w, A1.x, A1.y, A1.z, A1.w,
                   A2.x, A2.y, A2.z, A2.w, A3.x, A3.y, A3.z, A3.w};
    float m = e[0];
#pragma unroll
    for (int i = 1; i < 16; ++i) m = fmaxf(m, e[i]);
    float s = 0.f;
#pragma unroll
    for (int i = 0; i < 16; ++i) { e[i] = __expf(e[i] - m); s += e[i]; }
    const float inv = 1.f / s;
#pragma unroll
    for (int i = 0; i < 16; ++i) e[i] *= inv;

    f32x2 acc2[4] = {{0.f, 0.f}, {0.f, 0.f}, {0.f, 0.f}, {0.f, 0.f}};

#pragma unroll
    for (int l = 0; l < NLVL; ++l) {
        const float bx = (l == 0 ? rp.x : rp.z) * (float)WWID - 0.5f;
        const float by = (l == 0 ? rp.y : rp.w) * (float)HH - 0.5f;
        // +131 cells folds the (+1,+1) pad shift into the base
        const unsigned char* base = v2 + (size_t)(l * NHEADS + h) * MAPB
                                       + 131 * CELLB + ck * 8;
        const float* offp = qrow + h * 32 + l * 16;

        float4 o0 = *reinterpret_cast<const float4*>(offp);
        float4 o1 = *reinterpret_cast<const float4*>(offp + 4);
        float4 o2 = *reinterpret_cast<const float4*>(offp + 8);
        float4 o3 = *reinterpret_cast<const float4*>(offp + 12);
        const float ox[8] = {o0.x, o0.z, o1.x, o1.z, o2.x, o2.z, o3.x, o3.z};
        const float oy[8] = {o0.y, o0.w, o1.y, o1.w, o2.y, o2.w, o3.y, o3.w};

#pragma unroll
        for (int p = 0; p < NPTS; ++p) {
            const float px = bx + ox[p];
            const float py = by + oy[p];
            const float w  = e[l * 8 + p];
            const float x0f = floorf(px), y0f = floorf(py);
            const int x0 = (int)x0f, y0 = (int)y0f;
            const float wx1 = px - x0f, wy1 = py - y0f;
            const float wx0 = 1.f - wx1, wy0 = 1.f - wy1;
            const int x0c = min(max(x0, -1), 128);
            const int x1c = min(max(x0 + 1, -1), 128);
            const int y0c = min(max(y0, -1), 128);
            const int y1c = min(max(y0 + 1, -1), 128);
            const unsigned char* r0 = base + y0c * ROWB;
            const unsigned char* r1 = base + y1c * ROWB;
            uint2 u00 = *reinterpret_cast<const uint2*>(r0 + x0c * CELLB);
            uint2 u10 = *reinterpret_cast<const uint2*>(r0 + x1c * CELLB);
            uint2 u01 = *reinterpret_cast<const uint2*>(r1 + x0c * CELLB);
            uint2 u11 = *reinterpret_cast<const uint2*>(r1 + x1c * CELLB);
            const float wy0w = w * wy0, wy1w = w * wy1;
            acc_tap(u00, wy0w * wx0, acc2);
            acc_tap(u10, wy0w * wx1, acc2);
            acc_tap(u01, wy1w * wx0, acc2);
            acc_tap(u11, wy1w * wx1, acc2);
        }
    }

    bf16x8 ov;
#pragma unroll
    for (int i = 0; i < 4; ++i) {
        ov[2 * i]     = f2b(acc2[i].x);
        ov[2 * i + 1] = f2b(acc2[i].y);
    }
    *reinterpret_cast<bf16x8*>(tmp + (size_t)q * CDIM + h * DHEAD + ck * 8) = ov;
}

// ---------------------------------------------------------------------------
extern "C" void kernel_launch(void* const* d_in, const int* in_sizes, int n_in,
                              void* d_out, int out_size, void* d_ws, size_t ws_size,
                              hipStream_t stream) {
    const float* query     = (const float*)d_in[0];
    const float* query_pos = (const float*)d_in[1];
    const float* value     = (const float*)d_in[2];
    const float* refp      = (const float*)d_in[3];
    // d_in[4] spatial_shapes: static 128x128, hard-coded
    const float* W_off  = (const float*)d_in[5];
    const float* b_off  = (const float*)d_in[6];
    const float* W_attn = (const float*)d_in[7];
    const float* b_attn = (const float*)d_in[8];
    const float* W_val  = (const float*)d_in[9];
    const float* b_val  = (const float*)d_in[10];
    const float* W_out  = (const float*)d_in[11];
    const float* b_out  = (const float*)d_in[12];
    float* out = (float*)d_out;

    char* ws = (char*)d_ws;
    unsigned char* v2 = (unsigned char*)(ws);             //  8,654,848 B (padded fp8)
    float*  cbuf    = (float*)(ws + 8654848);             // 25,165,824 B (16384x384 f32)
    bf16_t* tmp     = (bf16_t*)(ws + 33820672);           //  8,388,608 B
    bf16_t* Wt_val  = (bf16_t*)(ws + 42209280);           //    131,072 B (col-permuted)
    bf16_t* Wt_qa   = (bf16_t*)(ws + 42340352);           //    196,608 B (384x256)
    bf16_t* Wt_out  = (bf16_t*)(ws + 42536960);           //    131,072 B
    // total 42,668,032 B

    // zero v2 (incl. border) + transpose/convert all weights, one dispatch
    prep_k<<<MEMSET_BLKS + 224, 256, 0, stream>>>(W_val, W_off, W_attn, W_out,
                                                  v2, Wt_val, Wt_qa, Wt_out);
    // v2 (padded fp8 per-head maps) + cbuf (off|attn logits) in one dispatch
    fused_proj_k<<<896, 256, 0, stream>>>(value, query, query_pos,
                                          Wt_val, Wt_qa, b_val, b_off, b_attn,
                                          v2, cbuf);
    // softmax (in-register) + bilinear sampling -> tmp (16384 x 256) bf16
    sample_k<<<2048, 256, 0, stream>>>(v2, cbuf, refp, tmp);
    // out = tmp @ W_out + b_out + query (identity)
    outproj_k<<<256, 256, 0, stream>>>(tmp, Wt_out, b_out, query, out);
}

// Round 10
// 195.599 us; speedup vs baseline: 1.1320x; 1.1320x over previous
//
#include <hip/hip_runtime.h>
#include <hip/hip_bf16.h>
#include <math.h>

#define NQ     16384
#define CDIM   256
#define NHEADS 8
#define NPTS   8
#define NLVL   2
#define HH     128
#define WWID   128
#define DHEAD  32
#define NCAT   384   // fused off(256) + attn(128) projection width

// padded fp8 value-map geometry: (l, h, 130, 130, 32) fp8, zero border
#define PW        130
#define CELLB     32                    // bytes per cell (32 dims x fp8)
#define ROWB      (PW * CELLB)          // 4160 B per padded row
#define MAPB      (PW * PW * CELLB)     // 540800 B per (l,h) map
#define V2BYTES   (NLVL * NHEADS * MAPB)        // 8,652,800
#define MEMSET_BLKS 2113                // ceil(V2BYTES / (256*16))
#define TRANS_BLKS  224
#define CONVV_BLKS  4096                // value: 8,388,608 elems / 2048
#define CONVQ_BLKS  2048                // qsum:  4,194,304 elems / 2048

typedef __bf16 bf16_t;
typedef __bf16 bf16x8 __attribute__((ext_vector_type(8)));
typedef float  f32x4  __attribute__((ext_vector_type(4)));
typedef float  f32x2  __attribute__((ext_vector_type(2)));

typedef __attribute__((address_space(1))) const uint32_t gau32;
typedef __attribute__((address_space(3))) uint32_t lau32;

__device__ __forceinline__ bf16_t f2b(float f) { return (bf16_t)f; }

__device__ __forceinline__ bf16x8 cvt8(float4 a, float4 b) {
    bf16x8 v;
    v[0] = f2b(a.x); v[1] = f2b(a.y); v[2] = f2b(a.z); v[3] = f2b(a.w);
    v[4] = f2b(b.x); v[5] = f2b(b.y); v[6] = f2b(b.z); v[7] = f2b(b.w);
    return v;
}

// ---------------------------------------------------------------------------
// One dispatch: zero v2 + transpose weights + STREAM-CONVERT fp32 inputs to
// bf16 (value -> value_bf16 (in d_out), query+query_pos -> qsum).
// All conversion accesses are full-line contiguous (2 KB per wave-instr).
// W_val rows PERMUTED: n -> p(n) = (n&~63) | ((n&3)<<4) | ((n&63)>>2)
// ---------------------------------------------------------------------------
__global__ __launch_bounds__(256) void prep_k(const float* __restrict__ W_val,
                                              const float* __restrict__ W_off,
                                              const float* __restrict__ W_attn,
                                              const float* __restrict__ W_out,
                                              const float* __restrict__ value,
                                              const float* __restrict__ query,
                                              const float* __restrict__ query_pos,
                                              unsigned char* __restrict__ v2,
                                              bf16_t* __restrict__ Wt_val,
                                              bf16_t* __restrict__ Wt_qa,
                                              bf16_t* __restrict__ Wt_out,
                                              bf16_t* __restrict__ value_bf16,
                                              bf16_t* __restrict__ qsum) {
    const int b = blockIdx.x;
    if (b < MEMSET_BLKS) {
        size_t off = ((size_t)b * 256 + threadIdx.x) * 16;
        if (off < V2BYTES)
            *reinterpret_cast<uint4*>(v2 + off) = make_uint4(0, 0, 0, 0);
        return;
    }
    if (b < MEMSET_BLKS + TRANS_BLKS) {
        const int tb = b - MEMSET_BLKS;
        const float* W; bf16_t* Wt; int N, t; bool permute = false;
        if (tb < 64)       { W = W_val;  Wt = Wt_val;            N = 256; t = tb;       permute = true; }
        else if (tb < 128) { W = W_off;  Wt = Wt_qa;             N = 256; t = tb - 64;  }
        else if (tb < 160) { W = W_attn; Wt = Wt_qa + 256 * 256; N = 128; t = tb - 128; }
        else               { W = W_out;  Wt = Wt_out;            N = 256; t = tb - 160; }
        const int ntn = N >> 5;
        const int k0 = (t / ntn) * 32, n0 = (t % ntn) * 32;
        const int tx = threadIdx.x & 31, ty = threadIdx.x >> 5;   // 32 x 8
        __shared__ float s[32][33];
#pragma unroll
        for (int i = 0; i < 4; ++i)
            s[ty + 8 * i][tx] = W[(size_t)(k0 + ty + 8 * i) * N + n0 + tx];
        __syncthreads();
#pragma unroll
        for (int i = 0; i < 4; ++i) {
            const int n = n0 + ty + 8 * i;
            const int p = permute ? ((n & ~63) | ((n & 3) << 4) | ((n & 63) >> 2)) : n;
            Wt[(size_t)p * 256 + k0 + tx] = f2b(s[tx][ty + 8 * i]);
        }
        return;
    }
    if (b < MEMSET_BLKS + TRANS_BLKS + CONVV_BLKS) {
        const size_t off = ((size_t)(b - MEMSET_BLKS - TRANS_BLKS) * 256 + threadIdx.x) * 8;
        float4 a = *reinterpret_cast<const float4*>(value + off);
        float4 c = *reinterpret_cast<const float4*>(value + off + 4);
        *reinterpret_cast<bf16x8*>(value_bf16 + off) = cvt8(a, c);
        return;
    }
    {
        const size_t off =
            ((size_t)(b - MEMSET_BLKS - TRANS_BLKS - CONVV_BLKS) * 256 + threadIdx.x) * 8;
        float4 a0 = *reinterpret_cast<const float4*>(query + off);
        float4 a1 = *reinterpret_cast<const float4*>(query + off + 4);
        float4 b0 = *reinterpret_cast<const float4*>(query_pos + off);
        float4 b1 = *reinterpret_cast<const float4*>(query_pos + off + 4);
        a0.x += b0.x; a0.y += b0.y; a0.z += b0.z; a0.w += b0.w;
        a1.x += b1.x; a1.y += b1.y; a1.z += b1.z; a1.w += b1.w;
        *reinterpret_cast<bf16x8*>(qsum + off) = cvt8(a0, a1);
    }
}

// ---------------------------------------------------------------------------
// GEMM body, bf16 A via global_load_lds (m97-style full-line staging),
// XOR-swizzled LDS tiles (conflict-free staging + fragment reads).
// PERM_V: epilogue packs 4 fp8 bytes -> 1 dword into the padded v2 map
//         (requires the permuted Wt_val; logical col = colBase+wn+fr*4+j).
// ---------------------------------------------------------------------------
template <bool OUT_BF16, bool ADD_SRC, bool PERM_V>
__device__ __forceinline__ void gemm_body(bf16_t (&As)[128][64], bf16_t (&Bs)[128][64],
                                          int bidx, int bidy,
                                          const bf16_t* __restrict__ Abf,
                                          const bf16_t* __restrict__ Bt,
                                          const float* __restrict__ bias,
                                          const float* __restrict__ bias2,
                                          int Nsplit,
                                          const float* __restrict__ addsrc,
                                          void* __restrict__ Cout,
                                          int N, int K) {
    const int tid  = threadIdx.x;
    const int wave = tid >> 6;
    const int lane = tid & 63;
    const int rowBase = bidy * 128;
    const int colBase = bidx * 128;
    const int wm = (wave & 1) * 64;
    const int wn = (wave >> 1) * 64;
    const int fr = lane & 15;
    const int fq = lane >> 4;

    f32x4 acc[4][4] = {};

    const int lrow = lane >> 3;                       // 0..7
    const int scol = ((lane & 7) ^ lrow) * 8;         // swizzled k-offset (elems)

    for (int k0 = 0; k0 < K; k0 += 64) {
        __syncthreads();
#pragma unroll
        for (int t = 0; t < 4; ++t) {
            const bf16_t* src =
                Abf + (size_t)(rowBase + wave * 32 + t * 8 + lrow) * K + k0 + scol;
            __builtin_amdgcn_global_load_lds((gau32*)src,
                                             (lau32*)&As[wave * 32 + t * 8][0],
                                             16, 0, 0);
        }
#pragma unroll
        for (int t = 0; t < 4; ++t) {
            const bf16_t* src =
                Bt + (size_t)(colBase + wave * 32 + t * 8 + lrow) * K + k0 + scol;
            __builtin_amdgcn_global_load_lds((gau32*)src,
                                             (lau32*)&Bs[wave * 32 + t * 8][0],
                                             16, 0, 0);
        }
        __syncthreads();
#pragma unroll
        for (int ks = 0; ks < 2; ++ks) {
            const int gk = ((ks * 4 + fq) ^ (fr & 7)) * 8;  // swizzled read granule
            bf16x8 af[4], bfr[4];
#pragma unroll
            for (int i = 0; i < 4; ++i)
                af[i] = *reinterpret_cast<const bf16x8*>(&As[wm + i * 16 + fr][gk]);
#pragma unroll
            for (int j = 0; j < 4; ++j)
                bfr[j] = *reinterpret_cast<const bf16x8*>(&Bs[wn + j * 16 + fr][gk]);
#pragma unroll
            for (int i = 0; i < 4; ++i)
#pragma unroll
                for (int j = 0; j < 4; ++j)
                    acc[i][j] = __builtin_amdgcn_mfma_f32_16x16x32_bf16(af[i], bfr[j],
                                                                        acc[i][j], 0, 0, 0);
        }
    }

    if (PERM_V) {
        // logical cols for j=0..3 are lbase..lbase+3 (4 consecutive d, 1 head)
        const int lbase = colBase + wn + fr * 4;
        const float bv0 = bias[lbase], bv1 = bias[lbase + 1];
        const float bv2 = bias[lbase + 2], bv3 = bias[lbase + 3];
        const int hh = (lbase >> 5) & 7;
        const int dbase = lbase & 31;
        unsigned char* outp = (unsigned char*)Cout;
#pragma unroll
        for (int i = 0; i < 4; ++i) {
#pragma unroll
            for (int r = 0; r < 4; ++r) {
                const int row = rowBase + wm + i * 16 + fq * 4 + r;
                const int lv = row >> 14, cell = row & 16383;
                const int y = cell >> 7, x = cell & 127;
                uint32_t pk = __builtin_amdgcn_cvt_pk_fp8_f32(
                    acc[i][0][r] + bv0, acc[i][1][r] + bv1, 0, false);
                pk = (uint32_t)__builtin_amdgcn_cvt_pk_fp8_f32(
                    acc[i][2][r] + bv2, acc[i][3][r] + bv3, pk, true);
                *reinterpret_cast<uint32_t*>(
                    outp + (size_t)(lv * NHEADS + hh) * MAPB
                         + (size_t)(y + 1) * ROWB + (x + 1) * CELLB + dbase) = pk;
            }
        }
        return;
    }

    // epilogue: D[row = fq*4 + r][col = fr] per 16x16 tile
#pragma unroll
    for (int j = 0; j < 4; ++j) {
        const int col = colBase + wn + j * 16 + fr;
        const float bv = (col < Nsplit) ? bias[col] : bias2[col - Nsplit];
#pragma unroll
        for (int i = 0; i < 4; ++i) {
#pragma unroll
            for (int r = 0; r < 4; ++r) {
                const int row = rowBase + wm + i * 16 + fq * 4 + r;
                float vv = acc[i][j][r] + bv;
                if (ADD_SRC) vv += addsrc[(size_t)row * N + col];
                if (OUT_BF16)
                    ((bf16_t*)Cout)[(size_t)row * N + col] = f2b(vv);
                else
                    ((float*)Cout)[(size_t)row * N + col] = vv;
            }
        }
    }
}

// ---------------------------------------------------------------------------
// Fused projections, all-bf16 A. blocks 0..511: v-proj (value_bf16 ->
// padded fp8 v2, permuted Wt_val) | 512..895: qsum @ [W_off|W_attn] -> cbuf.
// Row-sharing block ids (diff by 8) land on the same XCD for A-tile L2 reuse.
// ---------------------------------------------------------------------------
__global__ __launch_bounds__(256, 4) void fused_proj_k(const bf16_t* __restrict__ value_bf16,
                                                       const bf16_t* __restrict__ qsum,
                                                       const bf16_t* __restrict__ Wt_val,
                                                       const bf16_t* __restrict__ Wt_qa,
                                                       const float* __restrict__ b_val,
                                                       const float* __restrict__ b_off,
                                                       const float* __restrict__ b_attn,
                                                       unsigned char* __restrict__ v2,
                                                       float* __restrict__ cbuf) {
    __shared__ __align__(16) bf16_t As[128][64];
    __shared__ __align__(16) bf16_t Bs[128][64];
    const int b = blockIdx.x;
    if (b < 512) {
        const int bidy = (b >> 4) * 8 + (b & 7);
        const int bidx = (b >> 3) & 1;
        gemm_body<true, false, true>(As, Bs, bidx, bidy, value_bf16,
                                     Wt_val, b_val, b_val, 256, nullptr, v2,
                                     CDIM, CDIM);
    } else {
        const int b2 = b - 512;
        const int bidy = (b2 / 24) * 8 + (b2 & 7);
        const int bidx = (b2 >> 3) % 3;
        gemm_body<false, false, false>(As, Bs, bidx, bidy, qsum,
                                       Wt_qa, b_off, b_attn, 256, nullptr, cbuf,
                                       NCAT, CDIM);
    }
}

// ---------------------------------------------------------------------------
// Output projection: out = tmp @ W_out + b_out + query
// ---------------------------------------------------------------------------
__global__ __launch_bounds__(256, 3) void outproj_k(const bf16_t* __restrict__ tmp,
                                                    const bf16_t* __restrict__ Wt_out,
                                                    const float* __restrict__ b_out,
                                                    const float* __restrict__ query,
                                                    float* __restrict__ out) {
    __shared__ __align__(16) bf16_t As[128][64];
    __shared__ __align__(16) bf16_t Bs[128][64];
    const int b = blockIdx.x;
    const int bidy = (b >> 4) * 8 + (b & 7);
    const int bidx = (b >> 3) & 1;
    gemm_body<false, true, false>(As, Bs, bidx, bidy, tmp,
                                  Wt_out, b_out, b_out, 256, query, out,
                                  CDIM, CDIM);
}

// ---------------------------------------------------------------------------
// Bilinear sampling on the zero-padded fp8 map. head = blockIdx % 8 -> XCD.
// Clamped taps land on zero cells => unconditional corner weights.
// fp8 -> f32 via v_cvt_pk_f32_fp8 (2 elems/inst), float2 accumulate.
// ---------------------------------------------------------------------------
__device__ __forceinline__ void acc_tap(uint2 u, float w, f32x2* acc2) {
    acc2[0] += __builtin_amdgcn_cvt_pk_f32_fp8((int)u.x, false) * w;
    acc2[1] += __builtin_amdgcn_cvt_pk_f32_fp8((int)u.x, true)  * w;
    acc2[2] += __builtin_amdgcn_cvt_pk_f32_fp8((int)u.y, false) * w;
    acc2[3] += __builtin_amdgcn_cvt_pk_f32_fp8((int)u.y, true)  * w;
}

__global__ __launch_bounds__(256) void sample_k(const unsigned char* __restrict__ v2,
                                                const float* __restrict__ cbuf,
                                                const float* __restrict__ refp,
                                                bf16_t* __restrict__ tmp) {
    const int b    = blockIdx.x;
    const int h    = b & 7;          // head -> XCD (round-robin dispatch)
    const int qblk = b >> 3;
    const int tid  = threadIdx.x;
    const int qloc = tid >> 2;
    const int ck   = tid & 3;
    const int q    = qblk * 64 + qloc;

    const float* qrow = cbuf + (size_t)q * NCAT;
    const float4 rp = *reinterpret_cast<const float4*>(refp + (size_t)q * 4);

    // ---- softmax over the 16 logits of (q,h), in-register ----
    const float* attp = qrow + 256 + h * 16;
    float4 A0 = *reinterpret_cast<const float4*>(attp);
    float4 A1 = *reinterpret_cast<const float4*>(attp + 4);
    float4 A2 = *reinterpret_cast<const float4*>(attp + 8);
    float4 A3 = *reinterpret_cast<const float4*>(attp + 12);
    float e[16] = {A0.x, A0.y, A0.z, A0.w, A1.x, A1.y, A1.z, A1.w,
                   A2.x, A2.y, A2.z, A2.w, A3.x, A3.y, A3.z, A3.w};
    float m = e[0];
#pragma unroll
    for (int i = 1; i < 16; ++i) m = fmaxf(m, e[i]);
    float s = 0.f;
#pragma unroll
    for (int i = 0; i < 16; ++i) { e[i] = __expf(e[i] - m); s += e[i]; }
    const float inv = 1.f / s;
#pragma unroll
    for (int i = 0; i < 16; ++i) e[i] *= inv;

    f32x2 acc2[4] = {{0.f, 0.f}, {0.f, 0.f}, {0.f, 0.f}, {0.f, 0.f}};

#pragma unroll
    for (int l = 0; l < NLVL; ++l) {
        const float bx = (l == 0 ? rp.x : rp.z) * (float)WWID - 0.5f;
        const float by = (l == 0 ? rp.y : rp.w) * (float)HH - 0.5f;
        // +131 cells folds the (+1,+1) pad shift into the base
        const unsigned char* base = v2 + (size_t)(l * NHEADS + h) * MAPB
                                       + 131 * CELLB + ck * 8;
        const float* offp = qrow + h * 32 + l * 16;

        float4 o0 = *reinterpret_cast<const float4*>(offp);
        float4 o1 = *reinterpret_cast<const float4*>(offp + 4);
        float4 o2 = *reinterpret_cast<const float4*>(offp + 8);
        float4 o3 = *reinterpret_cast<const float4*>(offp + 12);
        const float ox[8] = {o0.x, o0.z, o1.x, o1.z, o2.x, o2.z, o3.x, o3.z};
        const float oy[8] = {o0.y, o0.w, o1.y, o1.w, o2.y, o2.w, o3.y, o3.w};

#pragma unroll
        for (int p = 0; p < NPTS; ++p) {
            const float px = bx + ox[p];
            const float py = by + oy[p];
            const float w  = e[l * 8 + p];
            const float x0f = floorf(px), y0f = floorf(py);
            const int x0 = (int)x0f, y0 = (int)y0f;
            const float wx1 = px - x0f, wy1 = py - y0f;
            const float wx0 = 1.f - wx1, wy0 = 1.f - wy1;
            const int x0c = min(max(x0, -1), 128);
            const int x1c = min(max(x0 + 1, -1), 128);
            const int y0c = min(max(y0, -1), 128);
            const int y1c = min(max(y0 + 1, -1), 128);
            const unsigned char* r0 = base + y0c * ROWB;
            const unsigned char* r1 = base + y1c * ROWB;
            uint2 u00 = *reinterpret_cast<const uint2*>(r0 + x0c * CELLB);
            uint2 u10 = *reinterpret_cast<const uint2*>(r0 + x1c * CELLB);
            uint2 u01 = *reinterpret_cast<const uint2*>(r1 + x0c * CELLB);
            uint2 u11 = *reinterpret_cast<const uint2*>(r1 + x1c * CELLB);
            const float wy0w = w * wy0, wy1w = w * wy1;
            acc_tap(u00, wy0w * wx0, acc2);
            acc_tap(u10, wy0w * wx1, acc2);
            acc_tap(u01, wy1w * wx0, acc2);
            acc_tap(u11, wy1w * wx1, acc2);
        }
    }

    bf16x8 ov;
#pragma unroll
    for (int i = 0; i < 4; ++i) {
        ov[2 * i]     = f2b(acc2[i].x);
        ov[2 * i + 1] = f2b(acc2[i].y);
    }
    *reinterpret_cast<bf16x8*>(tmp + (size_t)q * CDIM + h * DHEAD + ck * 8) = ov;
}

// ---------------------------------------------------------------------------
extern "C" void kernel_launch(void* const* d_in, const int* in_sizes, int n_in,
                              void* d_out, int out_size, void* d_ws, size_t ws_size,
                              hipStream_t stream) {
    const float* query     = (const float*)d_in[0];
    const float* query_pos = (const float*)d_in[1];
    const float* value     = (const float*)d_in[2];
    const float* refp      = (const float*)d_in[3];
    // d_in[4] spatial_shapes: static 128x128, hard-coded
    const float* W_off  = (const float*)d_in[5];
    const float* b_off  = (const float*)d_in[6];
    const float* W_attn = (const float*)d_in[7];
    const float* b_attn = (const float*)d_in[8];
    const float* W_val  = (const float*)d_in[9];
    const float* b_val  = (const float*)d_in[10];
    const float* W_out  = (const float*)d_in[11];
    const float* b_out  = (const float*)d_in[12];
    float* out = (float*)d_out;

    char* ws = (char*)d_ws;
    unsigned char* v2 = (unsigned char*)(ws);             //  8,654,848 B (padded fp8)
    float*  cbuf    = (float*)(ws + 8654848);             // 25,165,824 B (16384x384 f32)
    bf16_t* tmp     = (bf16_t*)(ws + 33820672);           //  8,388,608 B (aliases qsum)
    bf16_t* Wt_val  = (bf16_t*)(ws + 42209280);           //    131,072 B (col-permuted)
    bf16_t* Wt_qa   = (bf16_t*)(ws + 42340352);           //    196,608 B (384x256)
    bf16_t* Wt_out  = (bf16_t*)(ws + 42536960);           //    131,072 B
    // total 42,668,032 B
    bf16_t* qsum       = tmp;            // dead before sample_k writes tmp
    bf16_t* value_bf16 = (bf16_t*)d_out; // d_out as scratch; overwritten by outproj

    // zero v2 + transpose weights + stream-convert value / (query+query_pos)
    prep_k<<<MEMSET_BLKS + TRANS_BLKS + CONVV_BLKS + CONVQ_BLKS, 256, 0, stream>>>(
        W_val, W_off, W_attn, W_out, value, query, query_pos,
        v2, Wt_val, Wt_qa, Wt_out, value_bf16, qsum);
    // v2 (padded fp8 per-head maps) + cbuf (off|attn logits) in one dispatch
    fused_proj_k<<<896, 256, 0, stream>>>(value_bf16, qsum,
                                          Wt_val, Wt_qa, b_val, b_off, b_attn,
                                          v2, cbuf);
    // softmax (in-register) + bilinear sampling -> tmp (16384 x 256) bf16
    sample_k<<<2048, 256, 0, stream>>>(v2, cbuf, refp, tmp);
    // out = tmp @ W_out + b_out + query (identity)
    outproj_k<<<256, 256, 0, stream>>>(tmp, Wt_out, b_out, query, out);
}

// Round 11
// 191.671 us; speedup vs baseline: 1.1552x; 1.0205x over previous
//
#include <hip/hip_runtime.h>
#include <hip/hip_bf16.h>
#include <math.h>

#define NQ     16384
#define CDIM   256
#define NHEADS 8
#define NPTS   8
#define NLVL   2
#define HH     128
#define WWID   128
#define DHEAD  32
#define NCAT   384   // fused off(256) + attn(128) projection width

// padded fp8 value-map geometry: (l, h, 130, 130, 32) fp8, zero border
#define PW        130
#define CELLB     32                    // bytes per cell (32 dims x fp8)
#define ROWB      (PW * CELLB)          // 4160 B per padded row
#define MAPB      (PW * PW * CELLB)     // 540800 B per (l,h) map
#define V2BYTES   (NLVL * NHEADS * MAPB)        // 8,652,800
#define MEMSET_BLKS 2113                // ceil(V2BYTES / (256*16))
#define TRANS_BLKS  224
#define CONVV_BLKS  4096                // value: 8,388,608 elems / 2048
#define CONVQ_BLKS  2048                // qsum:  4,194,304 elems / 2048

typedef __bf16 bf16_t;
typedef __bf16 bf16x8 __attribute__((ext_vector_type(8)));
typedef float  f32x4  __attribute__((ext_vector_type(4)));
typedef float  f32x2  __attribute__((ext_vector_type(2)));

typedef __attribute__((address_space(1))) const uint32_t gau32;
typedef __attribute__((address_space(3))) uint32_t lau32;

__device__ __forceinline__ bf16_t f2b(float f) { return (bf16_t)f; }

__device__ __forceinline__ bf16x8 cvt8(float4 a, float4 b) {
    bf16x8 v;
    v[0] = f2b(a.x); v[1] = f2b(a.y); v[2] = f2b(a.z); v[3] = f2b(a.w);
    v[4] = f2b(b.x); v[5] = f2b(b.y); v[6] = f2b(b.z); v[7] = f2b(b.w);
    return v;
}

// ---------------------------------------------------------------------------
// One dispatch: zero v2 + transpose weights + STREAM-CONVERT fp32 inputs to
// bf16 (value -> value_bf16 (in d_out), query+query_pos -> qsum).
// W_val rows PERMUTED: n -> p(n) = (n&~63) | ((n&3)<<4) | ((n&63)>>2)
// ---------------------------------------------------------------------------
__global__ __launch_bounds__(256) void prep_k(const float* __restrict__ W_val,
                                              const float* __restrict__ W_off,
                                              const float* __restrict__ W_attn,
                                              const float* __restrict__ W_out,
                                              const float* __restrict__ value,
                                              const float* __restrict__ query,
                                              const float* __restrict__ query_pos,
                                              unsigned char* __restrict__ v2,
                                              bf16_t* __restrict__ Wt_val,
                                              bf16_t* __restrict__ Wt_qa,
                                              bf16_t* __restrict__ Wt_out,
                                              bf16_t* __restrict__ value_bf16,
                                              bf16_t* __restrict__ qsum) {
    const int b = blockIdx.x;
    if (b < MEMSET_BLKS) {
        size_t off = ((size_t)b * 256 + threadIdx.x) * 16;
        if (off < V2BYTES)
            *reinterpret_cast<uint4*>(v2 + off) = make_uint4(0, 0, 0, 0);
        return;
    }
    if (b < MEMSET_BLKS + TRANS_BLKS) {
        const int tb = b - MEMSET_BLKS;
        const float* W; bf16_t* Wt; int N, t; bool permute = false;
        if (tb < 64)       { W = W_val;  Wt = Wt_val;            N = 256; t = tb;       permute = true; }
        else if (tb < 128) { W = W_off;  Wt = Wt_qa;             N = 256; t = tb - 64;  }
        else if (tb < 160) { W = W_attn; Wt = Wt_qa + 256 * 256; N = 128; t = tb - 128; }
        else               { W = W_out;  Wt = Wt_out;            N = 256; t = tb - 160; }
        const int ntn = N >> 5;
        const int k0 = (t / ntn) * 32, n0 = (t % ntn) * 32;
        const int tx = threadIdx.x & 31, ty = threadIdx.x >> 5;   // 32 x 8
        __shared__ float s[32][33];
#pragma unroll
        for (int i = 0; i < 4; ++i)
            s[ty + 8 * i][tx] = W[(size_t)(k0 + ty + 8 * i) * N + n0 + tx];
        __syncthreads();
#pragma unroll
        for (int i = 0; i < 4; ++i) {
            const int n = n0 + ty + 8 * i;
            const int p = permute ? ((n & ~63) | ((n & 3) << 4) | ((n & 63) >> 2)) : n;
            Wt[(size_t)p * 256 + k0 + tx] = f2b(s[tx][ty + 8 * i]);
        }
        return;
    }
    if (b < MEMSET_BLKS + TRANS_BLKS + CONVV_BLKS) {
        const size_t off = ((size_t)(b - MEMSET_BLKS - TRANS_BLKS) * 256 + threadIdx.x) * 8;
        float4 a = *reinterpret_cast<const float4*>(value + off);
        float4 c = *reinterpret_cast<const float4*>(value + off + 4);
        *reinterpret_cast<bf16x8*>(value_bf16 + off) = cvt8(a, c);
        return;
    }
    {
        const size_t off =
            ((size_t)(b - MEMSET_BLKS - TRANS_BLKS - CONVV_BLKS) * 256 + threadIdx.x) * 8;
        float4 a0 = *reinterpret_cast<const float4*>(query + off);
        float4 a1 = *reinterpret_cast<const float4*>(query + off + 4);
        float4 b0 = *reinterpret_cast<const float4*>(query_pos + off);
        float4 b1 = *reinterpret_cast<const float4*>(query_pos + off + 4);
        a0.x += b0.x; a0.y += b0.y; a0.z += b0.z; a0.w += b0.w;
        a1.x += b1.x; a1.y += b1.y; a1.z += b1.z; a1.w += b1.w;
        *reinterpret_cast<bf16x8*>(qsum + off) = cvt8(a0, a1);
    }
}

// ---------------------------------------------------------------------------
// GEMM body, bf16 A via global_load_lds (full-line staging), XOR-swizzled
// LDS tiles. PERM_V: packs 4 fp8 -> 1 dword into the padded v2 map.
// ---------------------------------------------------------------------------
template <bool OUT_BF16, bool ADD_SRC, bool PERM_V>
__device__ __forceinline__ void gemm_body(bf16_t (&As)[128][64], bf16_t (&Bs)[128][64],
                                          int bidx, int bidy,
                                          const bf16_t* __restrict__ Abf,
                                          const bf16_t* __restrict__ Bt,
                                          const float* __restrict__ bias,
                                          const float* __restrict__ bias2,
                                          int Nsplit,
                                          const float* __restrict__ addsrc,
                                          void* __restrict__ Cout,
                                          int N, int K) {
    const int tid  = threadIdx.x;
    const int wave = tid >> 6;
    const int lane = tid & 63;
    const int rowBase = bidy * 128;
    const int colBase = bidx * 128;
    const int wm = (wave & 1) * 64;
    const int wn = (wave >> 1) * 64;
    const int fr = lane & 15;
    const int fq = lane >> 4;

    f32x4 acc[4][4] = {};

    const int lrow = lane >> 3;                       // 0..7
    const int scol = ((lane & 7) ^ lrow) * 8;         // swizzled k-offset (elems)

    for (int k0 = 0; k0 < K; k0 += 64) {
        __syncthreads();
#pragma unroll
        for (int t = 0; t < 4; ++t) {
            const bf16_t* src =
                Abf + (size_t)(rowBase + wave * 32 + t * 8 + lrow) * K + k0 + scol;
            __builtin_amdgcn_global_load_lds((gau32*)src,
                                             (lau32*)&As[wave * 32 + t * 8][0],
                                             16, 0, 0);
        }
#pragma unroll
        for (int t = 0; t < 4; ++t) {
            const bf16_t* src =
                Bt + (size_t)(colBase + wave * 32 + t * 8 + lrow) * K + k0 + scol;
            __builtin_amdgcn_global_load_lds((gau32*)src,
                                             (lau32*)&Bs[wave * 32 + t * 8][0],
                                             16, 0, 0);
        }
        __syncthreads();
#pragma unroll
        for (int ks = 0; ks < 2; ++ks) {
            const int gk = ((ks * 4 + fq) ^ (fr & 7)) * 8;  // swizzled read granule
            bf16x8 af[4], bfr[4];
#pragma unroll
            for (int i = 0; i < 4; ++i)
                af[i] = *reinterpret_cast<const bf16x8*>(&As[wm + i * 16 + fr][gk]);
#pragma unroll
            for (int j = 0; j < 4; ++j)
                bfr[j] = *reinterpret_cast<const bf16x8*>(&Bs[wn + j * 16 + fr][gk]);
#pragma unroll
            for (int i = 0; i < 4; ++i)
#pragma unroll
                for (int j = 0; j < 4; ++j)
                    acc[i][j] = __builtin_amdgcn_mfma_f32_16x16x32_bf16(af[i], bfr[j],
                                                                        acc[i][j], 0, 0, 0);
        }
    }

    if (PERM_V) {
        const int lbase = colBase + wn + fr * 4;
        const float bv0 = bias[lbase], bv1 = bias[lbase + 1];
        const float bv2 = bias[lbase + 2], bv3 = bias[lbase + 3];
        const int hh = (lbase >> 5) & 7;
        const int dbase = lbase & 31;
        unsigned char* outp = (unsigned char*)Cout;
#pragma unroll
        for (int i = 0; i < 4; ++i) {
#pragma unroll
            for (int r = 0; r < 4; ++r) {
                const int row = rowBase + wm + i * 16 + fq * 4 + r;
                const int lv = row >> 14, cell = row & 16383;
                const int y = cell >> 7, x = cell & 127;
                uint32_t pk = __builtin_amdgcn_cvt_pk_fp8_f32(
                    acc[i][0][r] + bv0, acc[i][1][r] + bv1, 0, false);
                pk = (uint32_t)__builtin_amdgcn_cvt_pk_fp8_f32(
                    acc[i][2][r] + bv2, acc[i][3][r] + bv3, pk, true);
                *reinterpret_cast<uint32_t*>(
                    outp + (size_t)(lv * NHEADS + hh) * MAPB
                         + (size_t)(y + 1) * ROWB + (x + 1) * CELLB + dbase) = pk;
            }
        }
        return;
    }

    // epilogue: D[row = fq*4 + r][col = fr] per 16x16 tile
#pragma unroll
    for (int j = 0; j < 4; ++j) {
        const int col = colBase + wn + j * 16 + fr;
        const float bv = (col < Nsplit) ? bias[col] : bias2[col - Nsplit];
#pragma unroll
        for (int i = 0; i < 4; ++i) {
#pragma unroll
            for (int r = 0; r < 4; ++r) {
                const int row = rowBase + wm + i * 16 + fq * 4 + r;
                float vv = acc[i][j][r] + bv;
                if (ADD_SRC) vv += addsrc[(size_t)row * N + col];
                if (OUT_BF16)
                    ((bf16_t*)Cout)[(size_t)row * N + col] = f2b(vv);
                else
                    ((float*)Cout)[(size_t)row * N + col] = vv;
            }
        }
    }
}

// ---------------------------------------------------------------------------
// Fused projections. blocks 0..511: v-proj (value_bf16 -> padded fp8 v2,
// permuted Wt_val) | 512..895: qsum @ [W_off|W_attn] -> cbuf (bf16).
// ---------------------------------------------------------------------------
__global__ __launch_bounds__(256, 4) void fused_proj_k(const bf16_t* __restrict__ value_bf16,
                                                       const bf16_t* __restrict__ qsum,
                                                       const bf16_t* __restrict__ Wt_val,
                                                       const bf16_t* __restrict__ Wt_qa,
                                                       const float* __restrict__ b_val,
                                                       const float* __restrict__ b_off,
                                                       const float* __restrict__ b_attn,
                                                       unsigned char* __restrict__ v2,
                                                       bf16_t* __restrict__ cbuf) {
    __shared__ __align__(16) bf16_t As[128][64];
    __shared__ __align__(16) bf16_t Bs[128][64];
    const int b = blockIdx.x;
    if (b < 512) {
        const int bidy = (b >> 4) * 8 + (b & 7);
        const int bidx = (b >> 3) & 1;
        gemm_body<true, false, true>(As, Bs, bidx, bidy, value_bf16,
                                     Wt_val, b_val, b_val, 256, nullptr, v2,
                                     CDIM, CDIM);
    } else {
        const int b2 = b - 512;
        const int bidy = (b2 / 24) * 8 + (b2 & 7);
        const int bidx = (b2 >> 3) % 3;
        gemm_body<true, false, false>(As, Bs, bidx, bidy, qsum,
                                      Wt_qa, b_off, b_attn, 256, nullptr, cbuf,
                                      NCAT, CDIM);
    }
}

// ---------------------------------------------------------------------------
// Output projection: out = tmp @ W_out + b_out + query
// ---------------------------------------------------------------------------
__global__ __launch_bounds__(256, 3) void outproj_k(const bf16_t* __restrict__ tmp,
                                                    const bf16_t* __restrict__ Wt_out,
                                                    const float* __restrict__ b_out,
                                                    const float* __restrict__ query,
                                                    float* __restrict__ out) {
    __shared__ __align__(16) bf16_t As[128][64];
    __shared__ __align__(16) bf16_t Bs[128][64];
    const int b = blockIdx.x;
    const int bidy = (b >> 4) * 8 + (b & 7);
    const int bidx = (b >> 3) & 1;
    gemm_body<false, true, false>(As, Bs, bidx, bidy, tmp,
                                  Wt_out, b_out, b_out, 256, query, out,
                                  CDIM, CDIM);
}

// ---------------------------------------------------------------------------
// Bilinear sampling on the zero-padded fp8 map. head = blockIdx % 8 -> XCD.
// 2 threads per (q,h), 16 dims each: coord/softmax work duplicated only x2
// (was x4), corner gathers are uint4 (16 B, was 8 B). Clamped taps land on
// zero cells => unconditional corner weights. cbuf is bf16.
// ---------------------------------------------------------------------------
__device__ __forceinline__ void acc_tap4(uint4 u, float w, f32x2* acc2) {
    acc2[0] += __builtin_amdgcn_cvt_pk_f32_fp8((int)u.x, false) * w;
    acc2[1] += __builtin_amdgcn_cvt_pk_f32_fp8((int)u.x, true)  * w;
    acc2[2] += __builtin_amdgcn_cvt_pk_f32_fp8((int)u.y, false) * w;
    acc2[3] += __builtin_amdgcn_cvt_pk_f32_fp8((int)u.y, true)  * w;
    acc2[4] += __builtin_amdgcn_cvt_pk_f32_fp8((int)u.z, false) * w;
    acc2[5] += __builtin_amdgcn_cvt_pk_f32_fp8((int)u.z, true)  * w;
    acc2[6] += __builtin_amdgcn_cvt_pk_f32_fp8((int)u.w, false) * w;
    acc2[7] += __builtin_amdgcn_cvt_pk_f32_fp8((int)u.w, true)  * w;
}

__global__ __launch_bounds__(256) void sample_k(const unsigned char* __restrict__ v2,
                                                const bf16_t* __restrict__ cbuf,
                                                const float* __restrict__ refp,
                                                bf16_t* __restrict__ tmp) {
    const int b    = blockIdx.x;      // 1024 blocks
    const int h    = b & 7;           // head -> XCD (round-robin dispatch)
    const int qblk = b >> 3;          // 0..127
    const int tid  = threadIdx.x;
    const int qloc = tid >> 1;        // 0..127
    const int ck   = tid & 1;         // 16-dim half
    const int q    = qblk * 128 + qloc;

    const bf16_t* qrow = cbuf + (size_t)q * NCAT;
    const float4 rp = *reinterpret_cast<const float4*>(refp + (size_t)q * 4);

    // ---- softmax over the 16 logits of (q,h), in-register ----
    const bf16_t* attp = qrow + 256 + h * 16;
    bf16x8 A0 = *reinterpret_cast<const bf16x8*>(attp);
    bf16x8 A1 = *reinterpret_cast<const bf16x8*>(attp + 8);
    float e[16];
#pragma unroll
    for (int i = 0; i < 8; ++i) { e[i] = (float)A0[i]; e[8 + i] = (float)A1[i]; }
    float m = e[0];
#pragma unroll
    for (int i = 1; i < 16; ++i) m = fmaxf(m, e[i]);
    float s = 0.f;
#pragma unroll
    for (int i = 0; i < 16; ++i) { e[i] = __expf(e[i] - m); s += e[i]; }
    const float inv = 1.f / s;
#pragma unroll
    for (int i = 0; i < 16; ++i) e[i] *= inv;

    f32x2 acc2[8] = {};

#pragma unroll
    for (int l = 0; l < NLVL; ++l) {
        const float bx = (l == 0 ? rp.x : rp.z) * (float)WWID - 0.5f;
        const float by = (l == 0 ? rp.y : rp.w) * (float)HH - 0.5f;
        // +131 cells folds the (+1,+1) pad shift into the base
        const unsigned char* base = v2 + (size_t)(l * NHEADS + h) * MAPB
                                       + 131 * CELLB + ck * 16;
        const bf16_t* offp = qrow + h * 32 + l * 16;
        bf16x8 o0 = *reinterpret_cast<const bf16x8*>(offp);
        bf16x8 o1 = *reinterpret_cast<const bf16x8*>(offp + 8);
        float ox[8], oy[8];
#pragma unroll
        for (int i = 0; i < 4; ++i) {
            ox[i]     = (float)o0[2 * i];  oy[i]     = (float)o0[2 * i + 1];
            ox[4 + i] = (float)o1[2 * i];  oy[4 + i] = (float)o1[2 * i + 1];
        }

#pragma unroll
        for (int p = 0; p < NPTS; ++p) {
            const float px = bx + ox[p];
            const float py = by + oy[p];
            const float w  = e[l * 8 + p];
            const float x0f = floorf(px), y0f = floorf(py);
            const int x0 = (int)x0f, y0 = (int)y0f;
            const float wx1 = px - x0f, wy1 = py - y0f;
            const float wx0 = 1.f - wx1, wy0 = 1.f - wy1;
            const int x0c = min(max(x0, -1), 128);
            const int x1c = min(max(x0 + 1, -1), 128);
            const int y0c = min(max(y0, -1), 128);
            const int y1c = min(max(y0 + 1, -1), 128);
            const unsigned char* r0 = base + y0c * ROWB;
            const unsigned char* r1 = base + y1c * ROWB;
            uint4 u00 = *reinterpret_cast<const uint4*>(r0 + x0c * CELLB);
            uint4 u10 = *reinterpret_cast<const uint4*>(r0 + x1c * CELLB);
            uint4 u01 = *reinterpret_cast<const uint4*>(r1 + x0c * CELLB);
            uint4 u11 = *reinterpret_cast<const uint4*>(r1 + x1c * CELLB);
            const float wy0w = w * wy0, wy1w = w * wy1;
            acc_tap4(u00, wy0w * wx0, acc2);
            acc_tap4(u10, wy0w * wx1, acc2);
            acc_tap4(u01, wy1w * wx0, acc2);
            acc_tap4(u11, wy1w * wx1, acc2);
        }
    }

    bf16x8 ov0, ov1;
#pragma unroll
    for (int i = 0; i < 4; ++i) {
        ov0[2 * i]     = f2b(acc2[i].x);
        ov0[2 * i + 1] = f2b(acc2[i].y);
        ov1[2 * i]     = f2b(acc2[4 + i].x);
        ov1[2 * i + 1] = f2b(acc2[4 + i].y);
    }
    bf16_t* op = tmp + (size_t)q * CDIM + h * DHEAD + ck * 16;
    *reinterpret_cast<bf16x8*>(op)     = ov0;
    *reinterpret_cast<bf16x8*>(op + 8) = ov1;
}

// ---------------------------------------------------------------------------
extern "C" void kernel_launch(void* const* d_in, const int* in_sizes, int n_in,
                              void* d_out, int out_size, void* d_ws, size_t ws_size,
                              hipStream_t stream) {
    const float* query     = (const float*)d_in[0];
    const float* query_pos = (const float*)d_in[1];
    const float* value     = (const float*)d_in[2];
    const float* refp      = (const float*)d_in[3];
    // d_in[4] spatial_shapes: static 128x128, hard-coded
    const float* W_off  = (const float*)d_in[5];
    const float* b_off  = (const float*)d_in[6];
    const float* W_attn = (const float*)d_in[7];
    const float* b_attn = (const float*)d_in[8];
    const float* W_val  = (const float*)d_in[9];
    const float* b_val  = (const float*)d_in[10];
    const float* W_out  = (const float*)d_in[11];
    const float* b_out  = (const float*)d_in[12];
    float* out = (float*)d_out;

    char* ws = (char*)d_ws;
    unsigned char* v2 = (unsigned char*)(ws);             //  8,654,848 B (padded fp8)
    bf16_t* cbuf    = (bf16_t*)(ws + 8654848);            // 12,582,912 B (16384x384 bf16)
    bf16_t* tmp     = (bf16_t*)(ws + 21237760);           //  8,388,608 B (aliases qsum)
    bf16_t* Wt_val  = (bf16_t*)(ws + 29626368);           //    131,072 B (col-permuted)
    bf16_t* Wt_qa   = (bf16_t*)(ws + 29757440);           //    196,608 B (384x256)
    bf16_t* Wt_out  = (bf16_t*)(ws + 29954048);           //    131,072 B
    // total 30,085,120 B
    bf16_t* qsum       = tmp;            // dead before sample_k writes tmp
    bf16_t* value_bf16 = (bf16_t*)d_out; // d_out as scratch; overwritten by outproj

    // zero v2 + transpose weights + stream-convert value / (query+query_pos)
    prep_k<<<MEMSET_BLKS + TRANS_BLKS + CONVV_BLKS + CONVQ_BLKS, 256, 0, stream>>>(
        W_val, W_off, W_attn, W_out, value, query, query_pos,
        v2, Wt_val, Wt_qa, Wt_out, value_bf16, qsum);
    // v2 (padded fp8 per-head maps) + cbuf (off|attn logits, bf16)
    fused_proj_k<<<896, 256, 0, stream>>>(value_bf16, qsum,
                                          Wt_val, Wt_qa, b_val, b_off, b_attn,
                                          v2, cbuf);
    // softmax (in-register) + bilinear sampling -> tmp (16384 x 256) bf16
    sample_k<<<1024, 256, 0, stream>>>(v2, cbuf, refp, tmp);
    // out = tmp @ W_out + b_out + query (identity)
    outproj_k<<<256, 256, 0, stream>>>(tmp, Wt_out, b_out, query, out);
}